// Round 8
// baseline (119.841 us; speedup 1.0000x reference)
//
#include <hip/hip_runtime.h>

#define NXROWS 32768
#define NY     4096
#define MCOLS  16
#define BLOCK  256
#define KSPLIT 8
#define KCHUNK (NY / KSPLIT)               // 512
#define NITER  (KCHUNK / 32)               // 16
#define ROWS_PER_BLOCK 128                 // 4 waves x 32 rows
#define GRIDX  (NXROWS / ROWS_PER_BLOCK)   // 256 -> grid 256x8 = 2048 blocks = 8/CU

#define TPS_C 0.34657359027997264f  // 0.5*ln2: r^2 ln r = TPS_C * sq * log2(sq)

typedef __bf16 bf16x8 __attribute__((ext_vector_type(8)));
typedef short  s16x8  __attribute__((ext_vector_type(8)));
typedef float  f32x4  __attribute__((ext_vector_type(4)));

// ws layout (bytes). Pads absorb the unguarded last-iteration prefetch
// (garbage loaded, never consumed, stays inside ws).
//   [0,     65536)  y4 : 4096 x float4 (y0,y1,y2,|y|^2)   + 1KB pad
//   [66560, 197632) cT : bf16 [16][4096] = TPS_C * coeffs^T + 1KB pad
#define WS_Y4_OFF 0
#define WS_CT_OFF 66560
#define WS_END    (WS_CT_OFF + 131072 + 1024)

static __device__ __forceinline__ unsigned short f2bfu(float f) {
    __bf16 h = (__bf16)f;
    return __builtin_bit_cast(unsigned short, h);
}

// ---- prep: poly tail -> out (full overwrite), cT (TPS_C-scaled bf16
// transposed coeffs), y4. Branch ranges are multiples of BLOCK -> no
// intra-block divergence.
__global__ __launch_bounds__(BLOCK) void rbf_prep2(
    const float* __restrict__ y, const float* __restrict__ coeffs,
    const float* __restrict__ x, const float* __restrict__ shift,
    const float* __restrict__ scale, const int* __restrict__ powers, int nR,
    float4* __restrict__ y4, unsigned int* __restrict__ cTw,
    float* __restrict__ out)
{
    const int idx = blockIdx.x * BLOCK + threadIdx.x;
    if (idx < NXROWS * 4) {                       // poly tail -> out
        const int row = idx >> 2, mq = idx & 3;
        float xh[3];
        #pragma unroll
        for (int d = 0; d < 3; ++d)
            xh[d] = (x[row * 3 + d] - shift[d]) / scale[d];
        f32x4 s = {0.f, 0.f, 0.f, 0.f};
        for (int r = 0; r < nR; ++r) {
            float p = 1.0f;
            for (int d = 0; d < 3; ++d) {
                const int pw = powers[r * 3 + d];
                for (int k = 0; k < pw; ++k) p *= xh[d];
            }
            const f32x4 cv = *reinterpret_cast<const f32x4*>(
                coeffs + (size_t)(NY + r) * MCOLS + mq * 4);
            s += p * cv;
        }
        *reinterpret_cast<f32x4*>(out + (size_t)row * MCOLS + mq * 4) = s;
    } else if (idx < NXROWS * 4 + MCOLS * NY / 2) {   // cT build
        const int t  = idx - NXROWS * 4;
        const int m  = t >> 11;                   // 2048 j-pairs per m
        const int jp = (t & 2047) * 2;
        const unsigned short u0 = f2bfu(TPS_C * coeffs[(size_t)jp * MCOLS + m]);
        const unsigned short u1 = f2bfu(TPS_C * coeffs[(size_t)(jp + 1) * MCOLS + m]);
        cTw[((size_t)m * NY + jp) >> 1] = (unsigned int)u0 | ((unsigned int)u1 << 16);
    } else {                                      // y4 build
        const int j = idx - NXROWS * 4 - MCOLS * NY / 2;  // < NY
        const float y0 = y[3 * j], y1 = y[3 * j + 1], y2 = y[3 * j + 2];
        y4[j] = make_float4(y0, y1, y2, y0 * y0 + y1 * y1 + y2 * y2);
    }
}

// ---- main: per wave 2 M-tiles (32 rows); K in 32-steps via MFMA.
// A-frag: lane l -> row=l&15, k=(l>>4)*8+e ; B-frag: n=l&15, k=(l>>4)*8+e
// C/D:    lane l -> col=l&15, row=(l>>4)*4+reg   (m89-verified)
// Occupancy is the lever this round: grid 2048 blocks = 8/CU = 32 waves/CU.
__global__ __launch_bounds__(BLOCK, 8) void rbf_mfma2(
    const float* __restrict__ x, const float4* __restrict__ y4,
    const unsigned short* __restrict__ cT, float* __restrict__ out)
{
    const int lane = threadIdx.x & 63;
    const int wid  = threadIdx.x >> 6;
    const int n    = lane & 15;
    const int q    = lane >> 4;
    const int rowBase = blockIdx.x * ROWS_PER_BLOCK + wid * 32;
    const int r0 = rowBase + n;
    const int r1 = rowBase + 16 + n;
    const int kbase = blockIdx.y * KCHUNK;

    const float x00 = x[r0 * 3], x01 = x[r0 * 3 + 1], x02 = x[r0 * 3 + 2];
    const float x10 = x[r1 * 3], x11 = x[r1 * 3 + 1], x12 = x[r1 * 3 + 2];
    const float sx0 = x00 * x00 + x01 * x01 + x02 * x02;
    const float sx1 = x10 * x10 + x11 * x11 + x12 * x12;
    const float a00 = -2.f * x00, a01 = -2.f * x01, a02 = -2.f * x02;
    const float a10 = -2.f * x10, a11 = -2.f * x11, a12 = -2.f * x12;

    const float4* yb = y4 + kbase + q * 8;
    const unsigned short* cb = cT + (size_t)n * NY + kbase + q * 8;

    f32x4 acc0 = {0.f, 0.f, 0.f, 0.f}, acc1 = {0.f, 0.f, 0.f, 0.f};
    float4 yA[8], yB[8];
    s16x8 bA, bB;

#define LOADT(Y, B, K) do {                                              \
    _Pragma("unroll")                                                    \
    for (int e = 0; e < 8; ++e) Y[e] = yb[(K) + e];                      \
    B = *reinterpret_cast<const s16x8*>(cb + (K));                       \
} while (0)

#define CONSUME(Y, B) do {                                               \
    bf16x8 af0, af1;                                                     \
    _Pragma("unroll")                                                    \
    for (int e = 0; e < 8; ++e) {                                        \
        const float4 yv = Y[e];                                          \
        float s0 = fmaf(a00, yv.x, fmaf(a01, yv.y, fmaf(a02, yv.z, sx0 + yv.w))); \
        float s1 = fmaf(a10, yv.x, fmaf(a11, yv.y, fmaf(a12, yv.z, sx1 + yv.w))); \
        s0 = fmaxf(s0, 1e-14f);                                          \
        s1 = fmaxf(s1, 1e-14f);                                          \
        af0[e] = (__bf16)(s0 * __log2f(s0));                             \
        af1[e] = (__bf16)(s1 * __log2f(s1));                             \
    }                                                                    \
    const bf16x8 bf = __builtin_bit_cast(bf16x8, B);                     \
    acc0 = __builtin_amdgcn_mfma_f32_16x16x32_bf16(af0, bf, acc0, 0, 0, 0); \
    acc1 = __builtin_amdgcn_mfma_f32_16x16x32_bf16(af1, bf, acc1, 0, 0, 0); \
} while (0)

    LOADT(yA, bA, 0);
    for (int ks = 0; ks < NITER; ks += 2) {
        LOADT(yB, bB, (ks + 1) * 32);
        CONSUME(yA, bA);
        LOADT(yA, bA, (ks + 2) * 32);   // last prefetch reads ws pad; unused
        CONSUME(yB, bB);
    }
#undef LOADT
#undef CONSUME

    // no-return f32 atomic adds (fire-and-forget) on top of prep's poly init
    float* o0 = out + (size_t)(rowBase + q * 4) * MCOLS + n;
    float* o1 = out + (size_t)(rowBase + 16 + q * 4) * MCOLS + n;
    #pragma unroll
    for (int r = 0; r < 4; ++r) {
        atomicAdd(o0 + (size_t)r * MCOLS, acc0[r]);
        atomicAdd(o1 + (size_t)r * MCOLS, acc1[r]);
    }
}

// ---- fallback (ws too small; effectively never): pure f32 atomic path.
__global__ __launch_bounds__(BLOCK) void rbf_f32_atomic(
    const float* __restrict__ x, const float* __restrict__ y,
    const float* __restrict__ coeffs, float* __restrict__ out)
{
    const int jbase = blockIdx.y * 512;
    const int row = blockIdx.x * BLOCK + threadIdx.x;
    const float x0 = x[row * 3], x1 = x[row * 3 + 1], x2 = x[row * 3 + 2];
    float acc[MCOLS];
    #pragma unroll
    for (int m = 0; m < MCOLS; ++m) acc[m] = 0.f;
    const float4* c4 = reinterpret_cast<const float4*>(coeffs) + (size_t)jbase * 4;
    for (int j = 0; j < 512; ++j) {
        const float dx = x0 - y[(jbase + j) * 3 + 0];
        const float dy = x1 - y[(jbase + j) * 3 + 1];
        const float dz = x2 - y[(jbase + j) * 3 + 2];
        const float sq = fmaxf(dx * dx + dy * dy + dz * dz, 1e-14f);
        const float t = TPS_C * sq * __log2f(sq);
        #pragma unroll
        for (int g = 0; g < 4; ++g) {
            const float4 cv = c4[j * 4 + g];
            acc[g * 4 + 0] += t * cv.x; acc[g * 4 + 1] += t * cv.y;
            acc[g * 4 + 2] += t * cv.z; acc[g * 4 + 3] += t * cv.w;
        }
    }
    #pragma unroll
    for (int m = 0; m < MCOLS; ++m)
        atomicAdd(&out[(size_t)row * MCOLS + m], acc[m]);
}

__global__ __launch_bounds__(BLOCK) void rbf_poly_atomic(
    const float* __restrict__ x, const float* __restrict__ shift,
    const float* __restrict__ scale, const float* __restrict__ coeffs,
    const int* __restrict__ powers, int nR, float* __restrict__ out)
{
    const int idx = blockIdx.x * BLOCK + threadIdx.x;
    const int row = idx >> 2, mq = idx & 3;
    float xh[3];
    #pragma unroll
    for (int d = 0; d < 3; ++d) xh[d] = (x[row * 3 + d] - shift[d]) / scale[d];
    f32x4 s = {0.f, 0.f, 0.f, 0.f};
    for (int r = 0; r < nR; ++r) {
        float p = 1.0f;
        for (int d = 0; d < 3; ++d) {
            const int pw = powers[r * 3 + d];
            for (int k = 0; k < pw; ++k) p *= xh[d];
        }
        const f32x4 cv = *reinterpret_cast<const f32x4*>(
            coeffs + (size_t)(NY + r) * MCOLS + mq * 4);
        s += p * cv;
    }
    float* o = out + (size_t)row * MCOLS + mq * 4;
    atomicAdd(o + 0, s.x); atomicAdd(o + 1, s.y);
    atomicAdd(o + 2, s.z); atomicAdd(o + 3, s.w);
}

extern "C" void kernel_launch(void* const* d_in, const int* in_sizes, int n_in,
                              void* d_out, int out_size, void* d_ws, size_t ws_size,
                              hipStream_t stream) {
    const float* x      = (const float*)d_in[0];
    const float* y      = (const float*)d_in[1];
    const float* shift  = (const float*)d_in[2];
    const float* scale  = (const float*)d_in[3];
    const float* coeffs = (const float*)d_in[4];
    const int*   powers = (const int*)d_in[5];
    const int    nR     = in_sizes[5] / 3;
    float* out = (float*)d_out;

    if (ws_size >= WS_END) {
        char* ws = (char*)d_ws;
        float4*         y4  = (float4*)(ws + WS_Y4_OFF);
        unsigned short* cT  = (unsigned short*)(ws + WS_CT_OFF);
        unsigned int*   cTw = (unsigned int*)(ws + WS_CT_OFF);
        // prep: 131072 poly + 32768 cT + 4096 y4 threads = 656 blocks exactly
        rbf_prep2<<<(NXROWS * 4 + MCOLS * NY / 2 + NY) / BLOCK, BLOCK, 0, stream>>>(
            y, coeffs, x, shift, scale, powers, nR, y4, cTw, out);
        rbf_mfma2<<<dim3(GRIDX, KSPLIT), BLOCK, 0, stream>>>(x, y4, cT, out);
    } else {
        hipMemsetAsync(d_out, 0, (size_t)out_size * sizeof(float), stream);
        rbf_f32_atomic<<<dim3(NXROWS / BLOCK, NY / 512), BLOCK, 0, stream>>>(
            x, y, coeffs, out);
        rbf_poly_atomic<<<NXROWS * 4 / BLOCK, BLOCK, 0, stream>>>(
            x, shift, scale, coeffs, powers, nR, out);
    }
}

// Round 9
// 110.634 us; speedup vs baseline: 1.0832x; 1.0832x over previous
//
#include <hip/hip_runtime.h>

#define NXROWS 32768
#define NY     4096
#define MCOLS  16
#define BLOCK  256
#define KSPLIT 8
#define KCHUNK (NY / KSPLIT)               // 512
#define NITER  (KCHUNK / 32)               // 16
#define ROWS_PER_BLOCK 256                 // 4 waves x 4 tiles x 16 rows
#define GRIDX  (NXROWS / ROWS_PER_BLOCK)   // 128 -> grid 128x8 = 1024 blocks

#define TPS_C 0.34657359027997264f  // 0.5*ln2: r^2 ln r = TPS_C * sq * log2(sq)

typedef __bf16 bf16x8 __attribute__((ext_vector_type(8)));
typedef short  s16x8  __attribute__((ext_vector_type(8)));
typedef float  f32x4  __attribute__((ext_vector_type(4)));

// ws layout (bytes):
//   [0,      65536)   y4   : 4096 x float4 (y0,y1,y2,|y|^2)
//   [65536, 196608)   cT   : bf16 [16][4096] = TPS_C * coeffs^T
//   [262144, +16MiB)  part : f32 [KSPLIT][NXROWS][MCOLS]  (pure streamed writes)
#define WS_Y4_OFF   0
#define WS_CT_OFF   65536
#define WS_PART_OFF 262144
#define WS_END      (WS_PART_OFF + (size_t)KSPLIT * NXROWS * MCOLS * 4)

static __device__ __forceinline__ unsigned short f2bfu(float f) {
    __bf16 h = (__bf16)f;
    return __builtin_bit_cast(unsigned short, h);
}

// ---- prep: cT (TPS_C-scaled bf16 transposed coeffs) + y4. 144 blocks.
__global__ __launch_bounds__(BLOCK) void rbf_prep3(
    const float* __restrict__ y, const float* __restrict__ coeffs,
    float4* __restrict__ y4, unsigned int* __restrict__ cTw)
{
    const int idx = blockIdx.x * BLOCK + threadIdx.x;
    if (idx < MCOLS * NY / 2) {                   // cT build (u32-packed writes)
        const int m  = idx >> 11;                 // 2048 j-pairs per m
        const int jp = (idx & 2047) * 2;
        const unsigned short u0 = f2bfu(TPS_C * coeffs[(size_t)jp * MCOLS + m]);
        const unsigned short u1 = f2bfu(TPS_C * coeffs[(size_t)(jp + 1) * MCOLS + m]);
        cTw[((size_t)m * NY + jp) >> 1] = (unsigned int)u0 | ((unsigned int)u1 << 16);
    } else {                                      // y4 build
        const int j = idx - MCOLS * NY / 2;       // < NY
        const float y0 = y[3 * j], y1 = y[3 * j + 1], y2 = y[3 * j + 2];
        y4[j] = make_float4(y0, y1, y2, y0 * y0 + y1 * y1 + y2 * y2);
    }
}

// ---- main: per wave FOUR 16-row M-tiles (64 rows); K in 32-steps via MFMA.
// The 8 y4 loads + 1 cT load per K-step now feed 4 MFMAs (VMEM/pair halved
// vs R7/R8) and 4 independent log-chains (2x ILP).
// A-frag: lane l -> row=l&15, k=(l>>4)*8+e ; B-frag: n=l&15, k=(l>>4)*8+e
// C/D:    lane l -> col=l&15, row=(l>>4)*4+reg   (m89-verified)
__global__ __launch_bounds__(BLOCK, 4) void rbf_mfma4(
    const float* __restrict__ x, const float4* __restrict__ y4,
    const unsigned short* __restrict__ cT, float* __restrict__ part)
{
    const int lane = threadIdx.x & 63;
    const int wid  = threadIdx.x >> 6;
    const int n    = lane & 15;
    const int q    = lane >> 4;
    const int rowBase = blockIdx.x * ROWS_PER_BLOCK + wid * 64;
    const int kbase = blockIdx.y * KCHUNK;

    float sx[4], a0[4], a1[4], a2[4];
    #pragma unroll
    for (int t = 0; t < 4; ++t) {
        const int r = rowBase + t * 16 + n;
        const float c0 = x[r * 3], c1 = x[r * 3 + 1], c2 = x[r * 3 + 2];
        sx[t] = c0 * c0 + c1 * c1 + c2 * c2;
        a0[t] = -2.f * c0; a1[t] = -2.f * c1; a2[t] = -2.f * c2;
    }

    const float4* yb = y4 + kbase + q * 8;
    const unsigned short* cb = cT + (size_t)n * NY + kbase + q * 8;

    f32x4 acc[4];
    #pragma unroll
    for (int t = 0; t < 4; ++t) acc[t] = (f32x4){0.f, 0.f, 0.f, 0.f};

    for (int ks = 0; ks < NITER; ++ks) {
        float4 yv[8];
        #pragma unroll
        for (int e = 0; e < 8; ++e) yv[e] = yb[ks * 32 + e];
        const s16x8 braw = *reinterpret_cast<const s16x8*>(cb + ks * 32);

        bf16x8 af[4];
        #pragma unroll
        for (int e = 0; e < 8; ++e) {
            const float4 v = yv[e];
            #pragma unroll
            for (int t = 0; t < 4; ++t) {
                float s = fmaf(a0[t], v.x,
                          fmaf(a1[t], v.y,
                          fmaf(a2[t], v.z, sx[t] + v.w)));
                s = fmaxf(s, 1e-14f);
                af[t][e] = (__bf16)(s * __log2f(s));
            }
        }
        const bf16x8 bf = __builtin_bit_cast(bf16x8, braw);
        #pragma unroll
        for (int t = 0; t < 4; ++t)
            acc[t] = __builtin_amdgcn_mfma_f32_16x16x32_bf16(af[t], bf, acc[t], 0, 0, 0);
    }

    // streamed partial writes: 64-lane inst covers 4 rows x 16 cols = 256B
    float* plane = part + (size_t)blockIdx.y * NXROWS * MCOLS;
    #pragma unroll
    for (int t = 0; t < 4; ++t) {
        float* o = plane + (size_t)(rowBase + t * 16 + q * 4) * MCOLS + n;
        #pragma unroll
        for (int r = 0; r < 4; ++r) o[(size_t)r * MCOLS] = acc[t][r];
    }
}

// ---- reduce KSPLIT planes + polynomial tail; full overwrite of out.
__global__ __launch_bounds__(BLOCK) void rbf_reduce(
    const float* __restrict__ part, const float* __restrict__ x,
    const float* __restrict__ shift, const float* __restrict__ scale,
    const float* __restrict__ coeffs, const int* __restrict__ powers,
    int nR, float* __restrict__ out)
{
    const int idx = blockIdx.x * BLOCK + threadIdx.x;
    const int row = idx >> 2, mq = idx & 3;
    f32x4 s = {0.f, 0.f, 0.f, 0.f};
    #pragma unroll
    for (int sp = 0; sp < KSPLIT; ++sp) {
        const f32x4 v = *reinterpret_cast<const f32x4*>(
            part + (size_t)sp * NXROWS * MCOLS + (size_t)row * MCOLS + mq * 4);
        s += v;
    }
    float xh[3];
    #pragma unroll
    for (int d = 0; d < 3; ++d) xh[d] = (x[row * 3 + d] - shift[d]) / scale[d];
    for (int r = 0; r < nR; ++r) {
        float p = 1.0f;
        for (int d = 0; d < 3; ++d) {
            const int pw = powers[r * 3 + d];
            for (int k = 0; k < pw; ++k) p *= xh[d];
        }
        const f32x4 cv = *reinterpret_cast<const f32x4*>(
            coeffs + (size_t)(NY + r) * MCOLS + mq * 4);
        s += p * cv;
    }
    *reinterpret_cast<f32x4*>(out + (size_t)row * MCOLS + mq * 4) = s;
}

// ---- fallback (ws too small; effectively never): pure f32 atomic path.
__global__ __launch_bounds__(BLOCK) void rbf_f32_atomic(
    const float* __restrict__ x, const float* __restrict__ y,
    const float* __restrict__ coeffs, float* __restrict__ out)
{
    const int jbase = blockIdx.y * 512;
    const int row = blockIdx.x * BLOCK + threadIdx.x;
    const float x0 = x[row * 3], x1 = x[row * 3 + 1], x2 = x[row * 3 + 2];
    float acc[MCOLS];
    #pragma unroll
    for (int m = 0; m < MCOLS; ++m) acc[m] = 0.f;
    const float4* c4 = reinterpret_cast<const float4*>(coeffs) + (size_t)jbase * 4;
    for (int j = 0; j < 512; ++j) {
        const float dx = x0 - y[(jbase + j) * 3 + 0];
        const float dy = x1 - y[(jbase + j) * 3 + 1];
        const float dz = x2 - y[(jbase + j) * 3 + 2];
        const float sq = fmaxf(dx * dx + dy * dy + dz * dz, 1e-14f);
        const float t = TPS_C * sq * __log2f(sq);
        #pragma unroll
        for (int g = 0; g < 4; ++g) {
            const float4 cv = c4[j * 4 + g];
            acc[g * 4 + 0] += t * cv.x; acc[g * 4 + 1] += t * cv.y;
            acc[g * 4 + 2] += t * cv.z; acc[g * 4 + 3] += t * cv.w;
        }
    }
    #pragma unroll
    for (int m = 0; m < MCOLS; ++m)
        atomicAdd(&out[(size_t)row * MCOLS + m], acc[m]);
}

__global__ __launch_bounds__(BLOCK) void rbf_poly_atomic(
    const float* __restrict__ x, const float* __restrict__ shift,
    const float* __restrict__ scale, const float* __restrict__ coeffs,
    const int* __restrict__ powers, int nR, float* __restrict__ out)
{
    const int idx = blockIdx.x * BLOCK + threadIdx.x;
    const int row = idx >> 2, mq = idx & 3;
    float xh[3];
    #pragma unroll
    for (int d = 0; d < 3; ++d) xh[d] = (x[row * 3 + d] - shift[d]) / scale[d];
    f32x4 s = {0.f, 0.f, 0.f, 0.f};
    for (int r = 0; r < nR; ++r) {
        float p = 1.0f;
        for (int d = 0; d < 3; ++d) {
            const int pw = powers[r * 3 + d];
            for (int k = 0; k < pw; ++k) p *= xh[d];
        }
        const f32x4 cv = *reinterpret_cast<const f32x4*>(
            coeffs + (size_t)(NY + r) * MCOLS + mq * 4);
        s += p * cv;
    }
    float* o = out + (size_t)row * MCOLS + mq * 4;
    atomicAdd(o + 0, s.x); atomicAdd(o + 1, s.y);
    atomicAdd(o + 2, s.z); atomicAdd(o + 3, s.w);
}

extern "C" void kernel_launch(void* const* d_in, const int* in_sizes, int n_in,
                              void* d_out, int out_size, void* d_ws, size_t ws_size,
                              hipStream_t stream) {
    const float* x      = (const float*)d_in[0];
    const float* y      = (const float*)d_in[1];
    const float* shift  = (const float*)d_in[2];
    const float* scale  = (const float*)d_in[3];
    const float* coeffs = (const float*)d_in[4];
    const int*   powers = (const int*)d_in[5];
    const int    nR     = in_sizes[5] / 3;
    float* out = (float*)d_out;

    if (ws_size >= WS_END) {
        char* ws = (char*)d_ws;
        float4*         y4   = (float4*)(ws + WS_Y4_OFF);
        unsigned short* cT   = (unsigned short*)(ws + WS_CT_OFF);
        unsigned int*   cTw  = (unsigned int*)(ws + WS_CT_OFF);
        float*          part = (float*)(ws + WS_PART_OFF);
        rbf_prep3<<<(MCOLS * NY / 2 + NY) / BLOCK, BLOCK, 0, stream>>>(
            y, coeffs, y4, cTw);
        rbf_mfma4<<<dim3(GRIDX, KSPLIT), BLOCK, 0, stream>>>(x, y4, cT, part);
        rbf_reduce<<<NXROWS * 4 / BLOCK, BLOCK, 0, stream>>>(
            part, x, shift, scale, coeffs, powers, nR, out);
    } else {
        hipMemsetAsync(d_out, 0, (size_t)out_size * sizeof(float), stream);
        rbf_f32_atomic<<<dim3(NXROWS / BLOCK, NY / 512), BLOCK, 0, stream>>>(
            x, y, coeffs, out);
        rbf_poly_atomic<<<NXROWS * 4 / BLOCK, BLOCK, 0, stream>>>(
            x, shift, scale, coeffs, powers, nR, out);
    }
}